// Round 14
// baseline (81.049 us; speedup 1.0000x reference)
//
#include <hip/hip_runtime.h>
#include <math.h>

// Problem constants
#define B_N   2048
#define D_IN_ 16
#define Q_N   512
#define H_N   128

#define QCHUNK 32                      // q's per chunk
#define NQC    (Q_N / QCHUNK)          // 16
#define QPC    (QCHUNK / 4)            // 8 quads per chunk
#define NB     8                       // rows per thread
#define RPB    16                      // rows per block
#define NRB    (B_N / RPB)             // 128

static constexpr float kC = 2.88539008177792681472f;  // 2 * log2(e)

// ws layout (floats)
#define F_OFF   0                              // F[row*128+h], 262144
#define C4_OFF  (B_N * H_N)                    // float4 c4[...], 131072 floats
#define SC_OFF  (C4_OFF + NQC * QPC * 2 * H_N * 4)   // Sc[qc], 16
#define W2S_OFF (SC_OFF + NQC)                 // w2sum, 1
#define WS_FLOATS (W2S_OFF + 1)

// ---------------------------------------------------------------------------
// R14: single variable vs R13 — main_kernel __launch_bounds__(256,4)->(256,8)
// so all 2048 blocks are co-resident (256CU x 8) instead of two sequential
// occupancy waves. R13 ledger: headline 80.7 = floor(~66-68: fill 39.7 +
// reset ~25 + memset) + stage1(~2-3) + main(~8-10) + dispatch(~4).
// Main issue floor ~5.1us (512 fma + 64 qtr-rate rcp + ~150 epi per thread,
// 8 waves/SIMD); the 3-5us excess is latency/ramp — the (256,4) cap forced
// 2 waves of blocks. NOT a rerun of R8's null: that tested the fat fused
// kernel (VALU-saturated); lean main is a different regime (rule 23).
// Predict 78.5-79.5 if latency-exposed; flat => issue-bound at floor, ~2-3us
// structural left; worse => 64-VGPR spill, revert.
//   Math (verified in-harness R4/R10/R12/R13, absmax 0.0):
//   out[b] = sum_qc [ Sc*(w2sum+b2) + sum_h W2[h] * sum_qd N(F)/P(F) ]
// ---------------------------------------------------------------------------
__global__ __launch_bounds__(256, 4) void precompute_kernel(
    const float* __restrict__ input,
    const float* __restrict__ eq,
    const float* __restrict__ qx,
    const float* __restrict__ W1,
    const float* __restrict__ b1,
    const float* __restrict__ W2,
    float* __restrict__ ws)
{
    const int t = threadIdx.x;
    const int blk = blockIdx.x;

    if (blk < 1024) {
        // ---- F table: 2 rows per block, thread = (row, h) ----
        const int row = blk * 2 + (t >> 7);
        const int h   = t & 127;
        const float* inr = input + row * D_IN_;
        float s = 0.0f;
        #pragma unroll
        for (int d = 0; d < D_IN_; ++d)
            s = fmaf(inr[d], W1[(2 + d) * H_N + h], s);
        ws[F_OFF + row * H_N + h] = __builtin_amdgcn_exp2f(s * kC);
        return;
    }

    // ---- coef blocks: one per q-chunk ----
    const int qc   = blk - 1024;
    const int h    = t & 127;
    const int bg   = t >> 7;
    const int lane = t & 63;
    const int w    = t >> 6;

    __shared__ float y_s[QCHUNK];

    if (w == 0) {                      // y + Sc (lanes < 32)
        float s = 0.0f;
        if (lane < QCHUNK) {
            const int q = qc * QCHUNK + lane;
            const float a  = fmaf(qx[2 * q + 1], eq[1], qx[2 * q] * eq[0]);
            const float yv = sinf(a);
            y_s[lane] = -2.0f * yv;
            s = yv;
        }
        #pragma unroll
        for (int off = 32; off >= 1; off >>= 1)
            s += __shfl_down(s, off, 64);
        if (lane == 0) ws[SC_OFF + qc] = s;
    }
    if (w == 1 && qc == 0) {           // w2sum (once globally)
        float s = W2[lane] + W2[64 + lane];
        #pragma unroll
        for (int off = 32; off >= 1; off >>= 1)
            s += __shfl_down(s, off, 64);
        if (lane == 0) ws[W2S_OFF] = s;
    }
    __syncthreads();

    // thread (h,bg) builds quads bg*4+{0..3} — identical recurrence to R12
    const float w1a = W1[h], w1b = W1[H_N + h], bh = b1[h];
    float4* c4 = (float4*)(ws + C4_OFF);
    #pragma unroll
    for (int k = 0; k < 4; ++k) {
        const int qd = bg * 4 + k;
        float n0 = 0, n1 = 0, n2 = 0, n3 = 0;
        float p1 = 0, p2 = 0, p3 = 0, p4 = 0;
        #pragma unroll
        for (int i = 0; i < 4; ++i) {
            const int ql = qd * 4 + i;
            const float x0 = qx[qc * (QCHUNK * 2) + 2 * ql];
            const float x1 = qx[qc * (QCHUNK * 2) + 2 * ql + 1];
            const float u = fmaf(x1, w1b, fmaf(x0, w1a, bh));
            const float E = __builtin_amdgcn_exp2f(u * kC);
            const float y = y_s[ql];
            n3 = fmaf(E, n2, fmaf(y, p3, n3));
            n2 = fmaf(E, n1, fmaf(y, p2, n2));
            n1 = fmaf(E, n0, fmaf(y, p1, n1));
            n0 = n0 + y;
            p4 = fmaf(E, p3, p4);
            p3 = fmaf(E, p2, p3);
            p2 = fmaf(E, p1, p2);
            p1 = p1 + E;
        }
        const int base = (qc * QPC + qd) * 2;
        c4[(base + 0) * H_N + h] = make_float4(n0, n1, n2, n3);
        c4[(base + 1) * H_N + h] = make_float4(p1, p2, p3, p4);
    }
}

// ---------------------------------------------------------------------------
__global__ __launch_bounds__(256, 8) void main_kernel(
    const float* __restrict__ ws,
    const float* __restrict__ W2,
    const float* __restrict__ b2,
    float* __restrict__ out)
{
    __shared__ float part[4][NB];

    const int t    = threadIdx.x;
    const int rb   = blockIdx.x & (NRB - 1); // row-block [0,128)
    const int qc   = blockIdx.x >> 7;        // q-chunk   [0,16)
    const int h    = t & 127;
    const int bg   = t >> 7;
    const int lane = t & 63;
    const int w    = t >> 6;

    const float w2 = W2[h];

    // F for my 8 rows (coalesced: 64 lanes read consecutive h)
    float F[NB], acc[NB];
    #pragma unroll
    for (int r = 0; r < NB; ++r) {
        const int row = rb * RPB + bg * NB + r;
        F[r]   = ws[F_OFF + row * H_N + h];
        acc[r] = 0.0f;
    }

    // rational loop over this chunk's 8 quads; coefs from L2-resident table
    const float4* c4 = (const float4*)(ws + C4_OFF);
    #pragma unroll 2
    for (int qd = 0; qd < QPC; ++qd) {
        const int base = (qc * QPC + qd) * 2;
        const float4 cn = c4[(base + 0) * H_N + h];   // n0,n1,n2,n3
        const float4 cp = c4[(base + 1) * H_N + h];   // p1,p2,p3,p4
        #pragma unroll
        for (int r = 0; r < NB; ++r) {
            const float Fr  = F[r];
            const float den = fmaf(fmaf(fmaf(fmaf(cp.w, Fr, cp.z), Fr, cp.y), Fr, cp.x), Fr, 1.0f);
            const float num = fmaf(fmaf(fmaf(cn.w, Fr, cn.z), Fr, cn.y), Fr, cn.x);
            acc[r] = fmaf(num, __builtin_amdgcn_rcpf(den), acc[r]);
        }
    }

    // epilogue: x W2[h], reduce over h, add per-chunk constant
    #pragma unroll
    for (int r = 0; r < NB; ++r) {
        float p = acc[r] * w2;
        #pragma unroll
        for (int off = 32; off >= 1; off >>= 1)
            p += __shfl_down(p, off, 64);
        if (lane == 0) part[w][r] = p;
    }
    __syncthreads();

    if (t < 16) {
        const int r = t & 7, g = t >> 3;
        const float k0c = ws[SC_OFF + qc] * (ws[W2S_OFF] + b2[0]);
        const float s = part[2 * g][r] + part[2 * g + 1][r] + k0c;
        atomicAdd(out + rb * RPB + g * NB + r, s);
    }
}

// ---------------------------------------------------------------------------
// Fallback (= R12 kernel) if ws is ever too small. Kept for safety.
// ---------------------------------------------------------------------------
__global__ __launch_bounds__(256, 4) void fused_fallback(
    const float* __restrict__ input,
    const float* __restrict__ eq,
    const float* __restrict__ qx,
    const float* __restrict__ W1,
    const float* __restrict__ b1,
    const float* __restrict__ W2,
    const float* __restrict__ b2,
    float* __restrict__ out)
{
    __shared__ float4 c4_s[QPC * 256];
    __shared__ float in_s[RPB * D_IN_];
    __shared__ float qx_s[QCHUNK * 2];
    __shared__ float y_s[QCHUNK];
    __shared__ float part[4][NB];
    __shared__ float Sc_s, w2sum_s;

    const int t    = threadIdx.x;
    const int rb   = blockIdx.x & (NRB - 1);
    const int qc   = blockIdx.x >> 7;
    const int h    = t & 127;
    const int bg   = t >> 7;
    const int lane = t & 63;
    const int w    = t >> 6;
    const int cwn = (2 * h)     ^ (((2 * h)     >> 3) & 7);
    const int cwp = (2 * h + 1) ^ (((2 * h + 1) >> 3) & 7);

    in_s[t] = input[rb * (RPB * D_IN_) + t];
    if (t < QCHUNK * 2) qx_s[t] = qx[qc * (QCHUNK * 2) + t];
    if (w == 0) {
        float s = 0.0f;
        if (lane < QCHUNK) {
            const int q = qc * QCHUNK + lane;
            const float a  = fmaf(qx[2 * q + 1], eq[1], qx[2 * q] * eq[0]);
            const float yv = sinf(a);
            y_s[lane] = -2.0f * yv;
            s = yv;
        }
        #pragma unroll
        for (int off = 32; off >= 1; off >>= 1)
            s += __shfl_down(s, off, 64);
        if (lane == 0) Sc_s = s;
    }
    if (w == 1) {
        float s = W2[lane] + W2[64 + lane];
        #pragma unroll
        for (int off = 32; off >= 1; off >>= 1)
            s += __shfl_down(s, off, 64);
        if (lane == 0) w2sum_s = s;
    }
    const float w2 = W2[h];
    __syncthreads();

    {
        const float w1a = W1[h], w1b = W1[H_N + h], bh = b1[h];
        #pragma unroll
        for (int k = 0; k < 4; ++k) {
            const int qd = bg * 4 + k;
            float n0 = 0, n1 = 0, n2 = 0, n3 = 0;
            float p1 = 0, p2 = 0, p3 = 0, p4 = 0;
            #pragma unroll
            for (int i = 0; i < 4; ++i) {
                const int ql = qd * 4 + i;
                const float x0 = qx_s[2 * ql], x1 = qx_s[2 * ql + 1];
                const float u = fmaf(x1, w1b, fmaf(x0, w1a, bh));
                const float E = __builtin_amdgcn_exp2f(u * kC);
                const float y = y_s[ql];
                n3 = fmaf(E, n2, fmaf(y, p3, n3));
                n2 = fmaf(E, n1, fmaf(y, p2, n2));
                n1 = fmaf(E, n0, fmaf(y, p1, n1));
                n0 = n0 + y;
                p4 = fmaf(E, p3, p4);
                p3 = fmaf(E, p2, p3);
                p2 = fmaf(E, p1, p2);
                p1 = p1 + E;
            }
            float4* dst = c4_s + qd * 256;
            dst[cwn] = make_float4(n0, n1, n2, n3);
            dst[cwp] = make_float4(p1, p2, p3, p4);
        }
    }

    float F[NB], acc[NB];
    {
        float s[NB];
        #pragma unroll
        for (int r = 0; r < NB; ++r) s[r] = 0.0f;
        const float4* in4 = (const float4*)in_s;
        #pragma unroll
        for (int k = 0; k < 4; ++k) {
            const float wa = W1[(2 + 4 * k + 0) * H_N + h];
            const float wb = W1[(2 + 4 * k + 1) * H_N + h];
            const float wc = W1[(2 + 4 * k + 2) * H_N + h];
            const float wd = W1[(2 + 4 * k + 3) * H_N + h];
            #pragma unroll
            for (int r = 0; r < NB; ++r) {
                const float4 a = in4[(bg * NB + r) * 4 + k];
                float sr = s[r];
                sr = fmaf(a.x, wa, sr);
                sr = fmaf(a.y, wb, sr);
                sr = fmaf(a.z, wc, sr);
                sr = fmaf(a.w, wd, sr);
                s[r] = sr;
            }
        }
        #pragma unroll
        for (int r = 0; r < NB; ++r) {
            F[r] = __builtin_amdgcn_exp2f(s[r] * kC);
            acc[r] = 0.0f;
        }
    }
    __syncthreads();

    #pragma unroll 2
    for (int qd = 0; qd < QPC; ++qd) {
        const float4 cn = c4_s[qd * 256 + cwn];
        const float4 cp = c4_s[qd * 256 + cwp];
        #pragma unroll
        for (int r = 0; r < NB; ++r) {
            const float Fr  = F[r];
            const float den = fmaf(fmaf(fmaf(fmaf(cp.w, Fr, cp.z), Fr, cp.y), Fr, cp.x), Fr, 1.0f);
            const float num = fmaf(fmaf(fmaf(cn.w, Fr, cn.z), Fr, cn.y), Fr, cn.x);
            acc[r] = fmaf(num, __builtin_amdgcn_rcpf(den), acc[r]);
        }
    }

    #pragma unroll
    for (int r = 0; r < NB; ++r) {
        float p = acc[r] * w2;
        #pragma unroll
        for (int off = 32; off >= 1; off >>= 1)
            p += __shfl_down(p, off, 64);
        if (lane == 0) part[w][r] = p;
    }
    __syncthreads();

    if (t < 16) {
        const int r = t & 7, g = t >> 3;
        const float k0c = Sc_s * (w2sum_s + b2[0]);
        const float s = part[2 * g][r] + part[2 * g + 1][r] + k0c;
        atomicAdd(out + rb * RPB + g * NB + r, s);
    }
}

// ---------------------------------------------------------------------------
extern "C" void kernel_launch(void* const* d_in, const int* in_sizes, int n_in,
                              void* d_out, int out_size, void* d_ws, size_t ws_size,
                              hipStream_t stream)
{
    (void)in_sizes; (void)n_in;
    const float* input = (const float*)d_in[0];
    const float* eq    = (const float*)d_in[1];
    const float* qx    = (const float*)d_in[2];
    const float* W1    = (const float*)d_in[3];
    const float* b1    = (const float*)d_in[4];
    const float* W2    = (const float*)d_in[5];
    const float* b2    = (const float*)d_in[6];
    float* out = (float*)d_out;

    hipMemsetAsync(d_out, 0, (size_t)out_size * sizeof(float), stream);

    if (d_ws != nullptr && ws_size >= (size_t)WS_FLOATS * sizeof(float)) {
        float* ws = (float*)d_ws;
        precompute_kernel<<<dim3(1024 + NQC), dim3(256), 0, stream>>>(
            input, eq, qx, W1, b1, W2, ws);
        main_kernel<<<dim3(NRB * NQC), dim3(256), 0, stream>>>(
            ws, W2, b2, out);
    } else {
        fused_fallback<<<dim3(NRB * NQC), dim3(256), 0, stream>>>(
            input, eq, qx, W1, b1, W2, b2, out);
    }
}

// Round 16
// 78.488 us; speedup vs baseline: 1.0326x; 1.0326x over previous
//
#include <hip/hip_runtime.h>
#include <math.h>

// Problem constants
#define B_N   2048
#define D_IN_ 16
#define Q_N   512
#define H_N   128

#define QCHUNK 32                      // q's per chunk
#define NQC    (Q_N / QCHUNK)          // 16
#define QPC    (QCHUNK / 4)            // 8 quads per chunk
#define NB     8                       // rows per thread
#define RPB    16                      // rows per block
#define NRB    (B_N / RPB)             // 128

static constexpr float kC = 2.88539008177792681472f;  // 2 * log2(e)

// ws layout (floats)
#define F_OFF   0                              // F[row*128+h], 262144
#define C4_OFF  (B_N * H_N)                    // float4 coefs, 131072 floats
#define WS_FLOATS (C4_OFF + NQC * QPC * 2 * H_N * 4)

// ---------------------------------------------------------------------------
// R15/R16: structural trim (resubmitted unchanged; R15 hit acquisition
// timeout; desk-checked: stream-order visibility, F packing, const-block
// syncs, and the S_total identity are all sound).
//  (a) memset dispatch ELIMINATED: sum_qc k0c = S_total*(w2sum+b2) is one
//      scalar for every row -> stage-1 const-block writes out[b] directly;
//      main atomicAdds partials on top. 3 dispatches -> 2. Main tail loses
//      k0c/Sc/w2sum entirely.
//  (b) stage-1 grid 1040 -> 529 (F packed 4 rows/block: 512 + 16 coef + 1
//      const): 1040 > 1024 = 256CU x 4 blk meant a 2nd occupancy wave for
//      16 stragglers; 529 is a single wave.
// Ledger (R13/R14): headline 80.7/81.0 = floor ~66-68 (fill 39.7 + reset
// ~25) + elastic ~13 (memset+stage1 2-3+main 8-10+2 dispatch). Occupancy
// levers measured null twice (R8 fat, R14 lean) -> closed. Main issue floor
// ~5-6us. Predict 77-79; flat => dispatch overhead < model, near practical
// ceiling; fail => revert R13.
//   Math: out[b] = S_total*(w2sum+b2) + sum_qc sum_h W2[h] sum_qd N(F)/P(F);
//   coef recurrence + F expression bit-identical to R13 (absmax 0.0 there).
// ---------------------------------------------------------------------------
__global__ __launch_bounds__(256, 4) void precompute_kernel(
    const float* __restrict__ input,
    const float* __restrict__ eq,
    const float* __restrict__ qx,
    const float* __restrict__ W1,
    const float* __restrict__ b1,
    const float* __restrict__ W2,
    const float* __restrict__ b2,
    float* __restrict__ ws,
    float* __restrict__ out)
{
    const int t = threadIdx.x;
    const int blk = blockIdx.x;

    if (blk < 512) {
        // ---- F table: 4 rows per block; thread = (h, rowpair) ----
        const int h  = t & 127;
        const int r0 = blk * 4 + (t >> 7);
        #pragma unroll
        for (int j = 0; j < 2; ++j) {
            const int row = r0 + 2 * j;
            const float* inr = input + row * D_IN_;
            float s = 0.0f;
            #pragma unroll
            for (int d = 0; d < D_IN_; ++d)
                s = fmaf(inr[d], W1[(2 + d) * H_N + h], s);
            ws[F_OFF + row * H_N + h] = __builtin_amdgcn_exp2f(s * kC);
        }
        return;
    }

    if (blk < 512 + NQC) {
        // ---- coef block: one per q-chunk (recurrence identical to R13) ----
        const int qc   = blk - 512;
        const int h    = t & 127;
        const int bg   = t >> 7;
        const int lane = t & 63;
        const int w    = t >> 6;

        __shared__ float y_s[QCHUNK];
        if (w == 0 && lane < QCHUNK) {
            const int q = qc * QCHUNK + lane;
            const float a = fmaf(qx[2 * q + 1], eq[1], qx[2 * q] * eq[0]);
            y_s[lane] = -2.0f * sinf(a);
        }
        __syncthreads();

        const float w1a = W1[h], w1b = W1[H_N + h], bh = b1[h];
        float4* c4 = (float4*)(ws + C4_OFF);
        #pragma unroll
        for (int k = 0; k < 4; ++k) {
            const int qd = bg * 4 + k;
            float n0 = 0, n1 = 0, n2 = 0, n3 = 0;
            float p1 = 0, p2 = 0, p3 = 0, p4 = 0;
            #pragma unroll
            for (int i = 0; i < 4; ++i) {
                const int ql = qd * 4 + i;
                const float x0 = qx[qc * (QCHUNK * 2) + 2 * ql];
                const float x1 = qx[qc * (QCHUNK * 2) + 2 * ql + 1];
                const float u = fmaf(x1, w1b, fmaf(x0, w1a, bh));
                const float E = __builtin_amdgcn_exp2f(u * kC);
                const float y = y_s[ql];
                n3 = fmaf(E, n2, fmaf(y, p3, n3));
                n2 = fmaf(E, n1, fmaf(y, p2, n2));
                n1 = fmaf(E, n0, fmaf(y, p1, n1));
                n0 = n0 + y;
                p4 = fmaf(E, p3, p4);
                p3 = fmaf(E, p2, p3);
                p2 = fmaf(E, p1, p2);
                p1 = p1 + E;
            }
            const int base = (qc * QPC + qd) * 2;
            c4[(base + 0) * H_N + h] = make_float4(n0, n1, n2, n3);
            c4[(base + 1) * H_N + h] = make_float4(p1, p2, p3, p4);
        }
        return;
    }

    // ---- const block (blk == 528): S_total, w2sum, out init ----
    {
        const int lane = t & 63;
        const int w    = t >> 6;
        __shared__ float red[4];
        __shared__ float w2s_s;

        float s = 0.0f;
        for (int q = t; q < Q_N; q += 256) {
            const float a = fmaf(qx[2 * q + 1], eq[1], qx[2 * q] * eq[0]);
            s += sinf(a);
        }
        #pragma unroll
        for (int off = 32; off >= 1; off >>= 1)
            s += __shfl_down(s, off, 64);
        if (lane == 0) red[w] = s;
        __syncthreads();

        if (w == 0) {
            float s2 = W2[lane] + W2[64 + lane];
            #pragma unroll
            for (int off = 32; off >= 1; off >>= 1)
                s2 += __shfl_down(s2, off, 64);
            if (lane == 0) w2s_s = s2;
        }
        __syncthreads();

        const float Stot = red[0] + red[1] + red[2] + red[3];
        const float c = Stot * (w2s_s + b2[0]);
        for (int i = t; i < B_N; i += 256)
            out[i] = c;
    }
}

// ---------------------------------------------------------------------------
__global__ __launch_bounds__(256, 8) void main_kernel(
    const float* __restrict__ ws,
    const float* __restrict__ W2,
    float* __restrict__ out)
{
    __shared__ float part[4][NB];

    const int t    = threadIdx.x;
    const int rb   = blockIdx.x & (NRB - 1); // row-block [0,128)
    const int qc   = blockIdx.x >> 7;        // q-chunk   [0,16)
    const int h    = t & 127;
    const int bg   = t >> 7;
    const int lane = t & 63;
    const int w    = t >> 6;

    const float w2 = W2[h];

    // F for my 8 rows (coalesced: 64 lanes read consecutive h)
    float F[NB], acc[NB];
    #pragma unroll
    for (int r = 0; r < NB; ++r) {
        const int row = rb * RPB + bg * NB + r;
        F[r]   = ws[F_OFF + row * H_N + h];
        acc[r] = 0.0f;
    }

    // rational loop over this chunk's 8 quads; coefs from L2-resident table
    const float4* c4 = (const float4*)(ws + C4_OFF);
    #pragma unroll 2
    for (int qd = 0; qd < QPC; ++qd) {
        const int base = (qc * QPC + qd) * 2;
        const float4 cn = c4[(base + 0) * H_N + h];   // n0,n1,n2,n3
        const float4 cp = c4[(base + 1) * H_N + h];   // p1,p2,p3,p4
        #pragma unroll
        for (int r = 0; r < NB; ++r) {
            const float Fr  = F[r];
            const float den = fmaf(fmaf(fmaf(fmaf(cp.w, Fr, cp.z), Fr, cp.y), Fr, cp.x), Fr, 1.0f);
            const float num = fmaf(fmaf(fmaf(cn.w, Fr, cn.z), Fr, cn.y), Fr, cn.x);
            acc[r] = fmaf(num, __builtin_amdgcn_rcpf(den), acc[r]);
        }
    }

    // epilogue: x W2[h], reduce over h, atomicAdd partial (const pre-added)
    #pragma unroll
    for (int r = 0; r < NB; ++r) {
        float p = acc[r] * w2;
        #pragma unroll
        for (int off = 32; off >= 1; off >>= 1)
            p += __shfl_down(p, off, 64);
        if (lane == 0) part[w][r] = p;
    }
    __syncthreads();

    if (t < 16) {
        const int r = t & 7, g = t >> 3;
        const float s = part[2 * g][r] + part[2 * g + 1][r];
        atomicAdd(out + rb * RPB + g * NB + r, s);
    }
}

// ---------------------------------------------------------------------------
// Fallback (= R12 fused kernel) if ws is ever too small. Kept for safety.
// ---------------------------------------------------------------------------
__global__ __launch_bounds__(256, 4) void fused_fallback(
    const float* __restrict__ input,
    const float* __restrict__ eq,
    const float* __restrict__ qx,
    const float* __restrict__ W1,
    const float* __restrict__ b1,
    const float* __restrict__ W2,
    const float* __restrict__ b2,
    float* __restrict__ out)
{
    __shared__ float4 c4_s[QPC * 256];
    __shared__ float in_s[RPB * D_IN_];
    __shared__ float qx_s[QCHUNK * 2];
    __shared__ float y_s[QCHUNK];
    __shared__ float part[4][NB];
    __shared__ float Sc_s, w2sum_s;

    const int t    = threadIdx.x;
    const int rb   = blockIdx.x & (NRB - 1);
    const int qc   = blockIdx.x >> 7;
    const int h    = t & 127;
    const int bg   = t >> 7;
    const int lane = t & 63;
    const int w    = t >> 6;
    const int cwn = (2 * h)     ^ (((2 * h)     >> 3) & 7);
    const int cwp = (2 * h + 1) ^ (((2 * h + 1) >> 3) & 7);

    in_s[t] = input[rb * (RPB * D_IN_) + t];
    if (t < QCHUNK * 2) qx_s[t] = qx[qc * (QCHUNK * 2) + t];
    if (w == 0) {
        float s = 0.0f;
        if (lane < QCHUNK) {
            const int q = qc * QCHUNK + lane;
            const float a  = fmaf(qx[2 * q + 1], eq[1], qx[2 * q] * eq[0]);
            const float yv = sinf(a);
            y_s[lane] = -2.0f * yv;
            s = yv;
        }
        #pragma unroll
        for (int off = 32; off >= 1; off >>= 1)
            s += __shfl_down(s, off, 64);
        if (lane == 0) Sc_s = s;
    }
    if (w == 1) {
        float s = W2[lane] + W2[64 + lane];
        #pragma unroll
        for (int off = 32; off >= 1; off >>= 1)
            s += __shfl_down(s, off, 64);
        if (lane == 0) w2sum_s = s;
    }
    const float w2 = W2[h];
    __syncthreads();

    {
        const float w1a = W1[h], w1b = W1[H_N + h], bh = b1[h];
        #pragma unroll
        for (int k = 0; k < 4; ++k) {
            const int qd = bg * 4 + k;
            float n0 = 0, n1 = 0, n2 = 0, n3 = 0;
            float p1 = 0, p2 = 0, p3 = 0, p4 = 0;
            #pragma unroll
            for (int i = 0; i < 4; ++i) {
                const int ql = qd * 4 + i;
                const float x0 = qx_s[2 * ql], x1 = qx_s[2 * ql + 1];
                const float u = fmaf(x1, w1b, fmaf(x0, w1a, bh));
                const float E = __builtin_amdgcn_exp2f(u * kC);
                const float y = y_s[ql];
                n3 = fmaf(E, n2, fmaf(y, p3, n3));
                n2 = fmaf(E, n1, fmaf(y, p2, n2));
                n1 = fmaf(E, n0, fmaf(y, p1, n1));
                n0 = n0 + y;
                p4 = fmaf(E, p3, p4);
                p3 = fmaf(E, p2, p3);
                p2 = fmaf(E, p1, p2);
                p1 = p1 + E;
            }
            float4* dst = c4_s + qd * 256;
            dst[cwn] = make_float4(n0, n1, n2, n3);
            dst[cwp] = make_float4(p1, p2, p3, p4);
        }
    }

    float F[NB], acc[NB];
    {
        float s[NB];
        #pragma unroll
        for (int r = 0; r < NB; ++r) s[r] = 0.0f;
        const float4* in4 = (const float4*)in_s;
        #pragma unroll
        for (int k = 0; k < 4; ++k) {
            const float wa = W1[(2 + 4 * k + 0) * H_N + h];
            const float wb = W1[(2 + 4 * k + 1) * H_N + h];
            const float wc = W1[(2 + 4 * k + 2) * H_N + h];
            const float wd = W1[(2 + 4 * k + 3) * H_N + h];
            #pragma unroll
            for (int r = 0; r < NB; ++r) {
                const float4 a = in4[(bg * NB + r) * 4 + k];
                float sr = s[r];
                sr = fmaf(a.x, wa, sr);
                sr = fmaf(a.y, wb, sr);
                sr = fmaf(a.z, wc, sr);
                sr = fmaf(a.w, wd, sr);
                s[r] = sr;
            }
        }
        #pragma unroll
        for (int r = 0; r < NB; ++r) {
            F[r] = __builtin_amdgcn_exp2f(s[r] * kC);
            acc[r] = 0.0f;
        }
    }
    __syncthreads();

    #pragma unroll 2
    for (int qd = 0; qd < QPC; ++qd) {
        const float4 cn = c4_s[qd * 256 + cwn];
        const float4 cp = c4_s[qd * 256 + cwp];
        #pragma unroll
        for (int r = 0; r < NB; ++r) {
            const float Fr  = F[r];
            const float den = fmaf(fmaf(fmaf(fmaf(cp.w, Fr, cp.z), Fr, cp.y), Fr, cp.x), Fr, 1.0f);
            const float num = fmaf(fmaf(fmaf(cn.w, Fr, cn.z), Fr, cn.y), Fr, cn.x);
            acc[r] = fmaf(num, __builtin_amdgcn_rcpf(den), acc[r]);
        }
    }

    #pragma unroll
    for (int r = 0; r < NB; ++r) {
        float p = acc[r] * w2;
        #pragma unroll
        for (int off = 32; off >= 1; off >>= 1)
            p += __shfl_down(p, off, 64);
        if (lane == 0) part[w][r] = p;
    }
    __syncthreads();

    if (t < 16) {
        const int r = t & 7, g = t >> 3;
        const float k0c = Sc_s * (w2sum_s + b2[0]);
        const float s = part[2 * g][r] + part[2 * g + 1][r] + k0c;
        atomicAdd(out + rb * RPB + g * NB + r, s);
    }
}

// ---------------------------------------------------------------------------
extern "C" void kernel_launch(void* const* d_in, const int* in_sizes, int n_in,
                              void* d_out, int out_size, void* d_ws, size_t ws_size,
                              hipStream_t stream)
{
    (void)in_sizes; (void)n_in;
    const float* input = (const float*)d_in[0];
    const float* eq    = (const float*)d_in[1];
    const float* qx    = (const float*)d_in[2];
    const float* W1    = (const float*)d_in[3];
    const float* b1    = (const float*)d_in[4];
    const float* W2    = (const float*)d_in[5];
    const float* b2    = (const float*)d_in[6];
    float* out = (float*)d_out;

    if (d_ws != nullptr && ws_size >= (size_t)WS_FLOATS * sizeof(float)) {
        float* ws = (float*)d_ws;
        // Stage 1 (529 blocks, single occupancy wave): F table, coef table,
        // and out[b] = S_total*(w2sum+b2) init (replaces memset dispatch).
        precompute_kernel<<<dim3(512 + NQC + 1), dim3(256), 0, stream>>>(
            input, eq, qx, W1, b1, W2, b2, ws, out);
        // Stage 2: pure rational loop, atomicAdd partials onto the constant.
        main_kernel<<<dim3(NRB * NQC), dim3(256), 0, stream>>>(
            ws, W2, out);
    } else {
        hipMemsetAsync(d_out, 0, (size_t)out_size * sizeof(float), stream);
        fused_fallback<<<dim3(NRB * NQC), dim3(256), 0, stream>>>(
            input, eq, qx, W1, b1, W2, b2, out);
    }
}